// Round 16
// baseline (202.282 us; speedup 1.0000x reference)
//
#include <hip/hip_runtime.h>

typedef _Float16 f16x8 __attribute__((ext_vector_type(8)));
typedef float f32x4 __attribute__((ext_vector_type(4)));

#define HDIM  128
#define NSTEP 64
#define NG    512   // 4H gate columns
#define NBLK  8     // recurrence blocks (CUs)
#define BPB   8     // batches per block

#define LOG2E 1.44269504088896340736f

__device__ __forceinline__ float rcpf(float x) { return __builtin_amdgcn_rcpf(x); }
// 2^(-x), single v_exp_f32 with free input modifier
__device__ __forceinline__ float exp2neg(float x) {
    float r; asm("v_exp_f32 %0, -%1" : "=v"(r) : "v"(x)); return r;
}
// round-to-nearest-even f16 pack
__device__ __forceinline__ unsigned int packh2(float a, float b) {
    union { _Float16 h[2]; unsigned int u; } x;
    x.h[0] = (_Float16)a; x.h[1] = (_Float16)b; return x.u;
}

// grid = 8 blocks x 256 threads (4 waves, 1 wave/SIMD). Block owns 8 batches.
// 4 waves x 8 col-tiles: LDS A-reads/CU = waves*8 = 32 (halved vs R13).
// B = 64 f16x8 pinned AGPR fragments (256 AGPRs; ~100 VGPRs alongside).
// Tile i (0..7) of wave w: gate g=i>>1, h-group hs=i&1,
//   col = g*128 + w*32 + hs*16 + lr.
// A-operand MIRROR (proven R13): a8 row = lr&7 -> D rows 8-15 dup 0-7; lane
// (lg,lr) owns batches (lg&1)*4+q at rows lg*4+q, h-group hs_own=lg>>1.
// NO cross-lane op reads the asm-MFMA destination (R9-R12 failure class).
//
// R14 NaN lesson: regalloc-materialized SrcC-init copies (acc=bias) landed
// inside the invisible asm-MFMA cluster with no hazard spacing, and 96 live
// loop VGPRs invited spill copies there too. Fix: kt=0 MFMA is the ZERO-C
// INTRINSIC (hazard-recognized by LLVM), kt>=1 tied-form asm (MFMA->MFMA
// SrcC chaining needs no waits); bias applied as scalar adds in the update
// (4 VGPRs instead of 32, zero per-step init copies).
__global__ __launch_bounds__(256, 1) void recur_k(
    const float* __restrict__ emb, const float* __restrict__ Wg,
    const float* __restrict__ bg,  float* __restrict__ outb) {
    __shared__ __align__(16) unsigned int state_s[2][BPB * 128]; // 2 x 4KB

    const int blk = blockIdx.x, t = threadIdx.x;
    const int w = t >> 6, l = t & 63;
    const int lg = l >> 4, lr = l & 15;     // k-group, row-in-tile
    const int mr = lr & 7;                  // mirrored A-row (batch) this lane reads

    // ---- B-fragments (one-time), prescaled; k = kt*32+lg*8+e;
    // input[k] = (k even) ? c[k/2] : h[k/2]  ->  W row = (k&1)?128+k/2:k/2 ----
    f16x8 B[8][8];
    #pragma unroll
    for (int i = 0; i < 8; ++i) {
        const int g = i >> 1, hs = i & 1;
        const float sc = (g == 3) ? 2.f * LOG2E : LOG2E;
        const int c = g * 128 + w * 32 + hs * 16 + lr;
        #pragma unroll
        for (int kt = 0; kt < 8; ++kt) {
            f16x8 v;
            #pragma unroll
            for (int e = 0; e < 8; ++e) {
                const int k = kt * 32 + lg * 8 + e;
                const int r = (k & 1) ? 128 + (k >> 1) : (k >> 1);
                v[e] = (_Float16)(Wg[r * NG + c] * sc);
            }
            B[i][kt] = v;
        }
    }
    #pragma unroll
    for (int i = 0; i < 8; ++i)
        #pragma unroll
        for (int kt = 0; kt < 8; ++kt)
            asm volatile("" : "+a"(B[i][kt]));   // materialize W in AGPRs

    // ---- per-lane scalar biases for the update (prescaled) ----
    const int hs_own = lg >> 1;
    const int b_base = (lg & 1) * 4;
    const int h_upd = w * 32 + hs_own * 16 + lr;
    const float bF = bg[0 * 128 + h_upd] * LOG2E;
    const float bI = bg[1 * 128 + h_upd] * LOG2E;
    const float bO = bg[2 * 128 + h_upd] * LOG2E;
    const float bC = bg[3 * 128 + h_upd] * (2.f * LOG2E);

    // ---- initial state buf0: word kw of batch = (emb_kw, 0) f16 ----
    for (int wd = t; wd < BPB * 128; wd += 256) {
        int batch = wd >> 7, kw = wd & 127;
        float ev = emb[(size_t)(blk * BPB + batch) * 64 * HDIM + kw];
        *(unsigned int*)((char*)state_s[0] + batch * 512 + ((kw * 4) ^ ((batch & 7) << 4)))
            = packh2(ev, 0.f);
    }

    float c4[4] = {0.f, 0.f, 0.f, 0.f};
    float ph4[4];
    int hoff[4];
    #pragma unroll
    for (int q = 0; q < 4; ++q)
        hoff[q] = (blk * BPB + b_base + q) * 65536 + h_upd;
    __syncthreads();

    for (int s = 0; s < NSTEP; ++s) {
        // ---- preload all 8 A-fragments, mirrored row mr = lr&7 ----
        const char* buf = (const char*)state_s[s & 1];
        f16x8 a8[8];
        #pragma unroll
        for (int kt = 0; kt < 8; ++kt)
            a8[kt] = *(const f16x8*)(buf + mr * 512 + ((kt * 64 + lg * 16) ^ ((mr & 7) << 4)));
        // ---- pipelined history store (prev step), drains under MFMA ----
        if (s > 0) {
            float* ob = outb + (size_t)(s - 1) * 1024;
            #pragma unroll
            for (int q = 0; q < 4; ++q) ob[hoff[q]] = ph4[q];
        }
        // ---- MFMA: kt=0 zero-C intrinsic (hazard-recognized), rest tied asm ----
        f32x4 acc[8];
        #pragma unroll
        for (int i = 0; i < 8; ++i)
            acc[i] = __builtin_amdgcn_mfma_f32_16x16x32_f16(
                a8[0], B[i][0], (f32x4){0.f, 0.f, 0.f, 0.f}, 0, 0, 0);
        #pragma unroll
        for (int kt = 1; kt < 8; ++kt) {
            #pragma unroll
            for (int i = 0; i < 8; ++i)
                asm volatile("v_mfma_f32_16x16x32_f16 %0, %1, %2, %0"
                    : "+v"(acc[i]) : "v"(a8[kt]), "a"(B[i][kt]));
        }
        asm volatile("s_nop 7\n\ts_nop 7"); // MFMA -> VALU read spacing
        __builtin_amdgcn_sched_barrier(0);  // pin consumers after the nops
        // ---- dense update: 4 (batch,h) pairs per lane, own-acc select ----
        char* bufn = (char*)state_s[(s + 1) & 1];
        #pragma unroll
        for (int q = 0; q < 4; ++q) {
            float F = rcpf(1.f + exp2neg(acc[0 + hs_own][q] + bF));
            float I = rcpf(1.f + exp2neg(acc[2 + hs_own][q] + bI));
            float O = rcpf(1.f + exp2neg(acc[4 + hs_own][q] + bO));
            float Dd = fmaf(2.f, rcpf(1.f + exp2neg(acc[6 + hs_own][q] + bC)), -1.f);
            float cn = fmaf(F, c4[q], I * Dd);
            float th = fmaf(2.f, rcpf(1.f + exp2neg(cn * (2.f * LOG2E))), -1.f);
            float hn = O * th;
            c4[q] = cn; ph4[q] = cn;
            const int batch = b_base + q;
            *(unsigned int*)(bufn + batch * 512 + ((4 * h_upd) ^ ((batch & 7) << 4)))
                = packh2(cn, hn);
        }
        __syncthreads();
    }
    // ---- flush last step's history ----
    {
        float* ob = outb + (size_t)63 * 1024;
        #pragma unroll
        for (int q = 0; q < 4; ++q) ob[hoff[q]] = ph4[q];
    }
}

// blocks 0..4095: (b*64+s) projection+expand. recur stashed c[b][s][0:128] in
// the first 512 B of this block's OWN 4 KB output region; read it, project,
// overwrite region with the projected row replicated 64x. No cross-block hazard.
// blocks 4096..4351: copy trip (1 MB) into the front of d_out.
__global__ __launch_bounds__(256) void proj_expand_k(const float* __restrict__ Wl,
                                                     const float* __restrict__ bl,
                                                     const float* __restrict__ trip,
                                                     float* __restrict__ trip_out,
                                                     float* __restrict__ outb) {
    const int bs = blockIdx.x, t = threadIdx.x;
    if (bs >= 4096) {   // trip copy: 256 blocks x 256 threads x 16 B
        int i = (bs - 4096) * 256 + t;
        ((float4*)trip_out)[i] = ((const float4*)trip)[i];
        return;
    }
    __shared__ float c_s[HDIM];
    __shared__ __align__(16) float pj[16];
    float* reg = outb + (size_t)bs * 1024;
    if (t < HDIM) c_s[t] = reg[t];
    __syncthreads();
    if (t < 16) {
        float a = bl[t];
        #pragma unroll 16
        for (int h = 0; h < HDIM; ++h) a = fmaf(c_s[h], Wl[h * 16 + t], a);
        pj[t] = a;
    }
    __syncthreads();
    float4 v = ((const float4*)pj)[t & 3];
    ((float4*)reg)[t] = v;   // 256 float4 = 64 rows x 16 floats
}

extern "C" void kernel_launch(void* const* d_in, const int* in_sizes, int n_in,
                              void* d_out, int out_size, void* d_ws, size_t ws_size,
                              hipStream_t stream) {
    const float* trip = (const float*)d_in[0];
    // d_in[1] = valid_len : unused by the reference computation
    const float* emb  = (const float*)d_in[2];
    const float* Wg   = (const float*)d_in[3];
    const float* bgp  = (const float*)d_in[4];
    const float* Wlp  = (const float*)d_in[5];
    const float* blp  = (const float*)d_in[6];
    float* out = (float*)d_out;

    // output = [trip (262144 floats) | big (4194304 floats)]
    recur_k<<<NBLK, 256, 0, stream>>>(emb, Wg, bgp, out + 262144);
    proj_expand_k<<<4096 + 256, 256, 0, stream>>>(Wlp, blp, trip, out, out + 262144);
}

// Round 17
// 76.818 us; speedup vs baseline: 2.6333x; 2.6333x over previous
//
#include <hip/hip_runtime.h>

typedef _Float16 f16x8 __attribute__((ext_vector_type(8)));
typedef float f32x4 __attribute__((ext_vector_type(4)));

#define HDIM  128
#define NSTEP 64
#define NG    512   // 4H gate columns
#define NBLK  16    // recurrence blocks (CUs)
#define BPB   4     // batches per block

#define LOG2E 1.44269504088896340736f

__device__ __forceinline__ float rcpf(float x) { return __builtin_amdgcn_rcpf(x); }
// 2^(-x), single v_exp_f32 with free input modifier
__device__ __forceinline__ float exp2neg(float x) {
    float r; asm("v_exp_f32 %0, -%1" : "=v"(r) : "v"(x)); return r;
}
// round-to-nearest-even f16 pack
__device__ __forceinline__ unsigned int packh2(float a, float b) {
    union { _Float16 h[2]; unsigned int u; } x;
    x.h[0] = (_Float16)a; x.h[1] = (_Float16)b; return x.u;
}

// grid = 16 blocks x 512 threads (8 waves, 2/SIMD) -- R13's proven geometry
// (4 tiles/wave = 128 pinned AGPRs; R14/R15 showed 8 tiles/wave = allocator
// trap). Block owns 4 batches. Tile i of wave w: col = i*128 + w*16 + lr.
// A-operand MIRROR, now 4-way: a8 row = lr&3 -> D row lg*4+q holds batch q.
// Lane (lg,lr) updates exactly ONE pair (batch=lg, h=w*16+lr) read from its
// OWN acc[i][lg] -- no cross-lane op touches the asm-MFMA destination
// (R9-R12 failure class). Update work per lane halved vs R13.
// State: per batch 128 words, word h = (c_h,h_h) f16, XOR-swizzled.
// W prescaled by log2e (cand 2log2e) -> raw v_exp_f32; bias as scalar adds
// in the update (R15-proven); kt=0 MFMA = zero-C intrinsic (hazard-visible),
// kt>=1 tied-form asm (MFMA->MFMA SrcC chaining needs no waits).
__global__ __launch_bounds__(512, 2) void recur_k(
    const float* __restrict__ emb, const float* __restrict__ Wg,
    const float* __restrict__ bg,  float* __restrict__ outb) {
    __shared__ __align__(16) unsigned int state_s[2][BPB * 128]; // 2 x 2KB

    const int blk = blockIdx.x, t = threadIdx.x;
    const int w = t >> 6, l = t & 63;
    const int lg = l >> 4, lr = l & 15;     // k-group, row-in-tile
    const int mr = lr & 3;                  // mirrored A-row (batch) this lane reads

    // ---- B-fragments (one-time), prescaled; k = kt*32+lg*8+e;
    // input[k] = (k even) ? c[k/2] : h[k/2]  ->  W row = (k&1)?128+k/2:k/2 ----
    f16x8 B[4][8];
    #pragma unroll
    for (int i = 0; i < 4; ++i) {
        const float sc = (i == 3) ? 2.f * LOG2E : LOG2E;
        const int c = i * 128 + w * 16 + lr;
        #pragma unroll
        for (int kt = 0; kt < 8; ++kt) {
            f16x8 v;
            #pragma unroll
            for (int e = 0; e < 8; ++e) {
                const int k = kt * 32 + lg * 8 + e;
                const int r = (k & 1) ? 128 + (k >> 1) : (k >> 1);
                v[e] = (_Float16)(Wg[r * NG + c] * sc);
            }
            B[i][kt] = v;
        }
    }
    #pragma unroll
    for (int i = 0; i < 4; ++i)
        #pragma unroll
        for (int kt = 0; kt < 8; ++kt)
            asm volatile("" : "+a"(B[i][kt]));   // materialize W in AGPRs

    // ---- per-lane scalar biases (prescaled); lane owns (batch=lg, h_upd) ----
    const int h_upd = w * 16 + lr;
    const float bF = bg[0 * 128 + h_upd] * LOG2E;
    const float bI = bg[1 * 128 + h_upd] * LOG2E;
    const float bO = bg[2 * 128 + h_upd] * LOG2E;
    const float bC = bg[3 * 128 + h_upd] * (2.f * LOG2E);

    // ---- initial state buf0: word kw of batch = (emb_kw, 0) f16 ----
    for (int wd = t; wd < BPB * 128; wd += 512) {
        int batch = wd >> 7, kw = wd & 127;
        float ev = emb[(size_t)(blk * BPB + batch) * 64 * HDIM + kw];
        *(unsigned int*)((char*)state_s[0] + batch * 512 + ((kw * 4) ^ ((batch & 7) << 4)))
            = packh2(ev, 0.f);
    }

    float c1 = 0.f;     // c state for (batch=lg, h_upd)
    float ph1;          // prev-step c (stored next step, hidden under MFMA)
    const int hoff = (blk * BPB + lg) * 65536 + h_upd;
    __syncthreads();

    for (int s = 0; s < NSTEP; ++s) {
        // ---- preload all 8 A-fragments, mirrored row mr = lr&3 ----
        const char* buf = (const char*)state_s[s & 1];
        f16x8 a8[8];
        #pragma unroll
        for (int kt = 0; kt < 8; ++kt)
            a8[kt] = *(const f16x8*)(buf + mr * 512 + ((kt * 64 + lg * 16) ^ ((mr & 7) << 4)));
        // ---- pipelined history store (prev step), drains under MFMA ----
        if (s > 0) outb[(size_t)(s - 1) * 1024 + hoff] = ph1;
        // ---- MFMA: kt=0 zero-C intrinsic (hazard-visible), rest tied asm ----
        f32x4 acc[4];
        #pragma unroll
        for (int i = 0; i < 4; ++i)
            acc[i] = __builtin_amdgcn_mfma_f32_16x16x32_f16(
                a8[0], B[i][0], (f32x4){0.f, 0.f, 0.f, 0.f}, 0, 0, 0);
        #pragma unroll
        for (int kt = 1; kt < 8; ++kt) {
            #pragma unroll
            for (int i = 0; i < 4; ++i)
                asm volatile("v_mfma_f32_16x16x32_f16 %0, %1, %2, %0"
                    : "+v"(acc[i]) : "v"(a8[kt]), "a"(B[i][kt]));
        }
        asm volatile("s_nop 7\n\ts_nop 7"); // MFMA -> VALU read spacing
        __builtin_amdgcn_sched_barrier(0);  // pin consumers after the nops
        // ---- update: ONE (batch=lg, h_upd) pair, own-acc select q=lg ----
        {
            float F = rcpf(1.f + exp2neg(acc[0][lg] + bF));
            float I = rcpf(1.f + exp2neg(acc[1][lg] + bI));
            float O = rcpf(1.f + exp2neg(acc[2][lg] + bO));
            float Dd = fmaf(2.f, rcpf(1.f + exp2neg(acc[3][lg] + bC)), -1.f);
            float cn = fmaf(F, c1, I * Dd);
            float th = fmaf(2.f, rcpf(1.f + exp2neg(cn * (2.f * LOG2E))), -1.f);
            float hn = O * th;
            c1 = cn; ph1 = cn;
            char* bufn = (char*)state_s[(s + 1) & 1];
            *(unsigned int*)(bufn + lg * 512 + ((4 * h_upd) ^ ((lg & 7) << 4)))
                = packh2(cn, hn);
        }
        __syncthreads();
    }
    // ---- flush last step's history ----
    outb[(size_t)63 * 1024 + hoff] = ph1;
}

// blocks 0..4095: (b*64+s) projection+expand. recur stashed c[b][s][0:128] in
// the first 512 B of this block's OWN 4 KB output region; read it, project,
// overwrite region with the projected row replicated 64x. No cross-block hazard.
// blocks 4096..4351: copy trip (1 MB) into the front of d_out.
__global__ __launch_bounds__(256) void proj_expand_k(const float* __restrict__ Wl,
                                                     const float* __restrict__ bl,
                                                     const float* __restrict__ trip,
                                                     float* __restrict__ trip_out,
                                                     float* __restrict__ outb) {
    const int bs = blockIdx.x, t = threadIdx.x;
    if (bs >= 4096) {   // trip copy: 256 blocks x 256 threads x 16 B
        int i = (bs - 4096) * 256 + t;
        ((float4*)trip_out)[i] = ((const float4*)trip)[i];
        return;
    }
    __shared__ float c_s[HDIM];
    __shared__ __align__(16) float pj[16];
    float* reg = outb + (size_t)bs * 1024;
    if (t < HDIM) c_s[t] = reg[t];
    __syncthreads();
    if (t < 16) {
        float a = bl[t];
        #pragma unroll 16
        for (int h = 0; h < HDIM; ++h) a = fmaf(c_s[h], Wl[h * 16 + t], a);
        pj[t] = a;
    }
    __syncthreads();
    float4 v = ((const float4*)pj)[t & 3];
    ((float4*)reg)[t] = v;   // 256 float4 = 64 rows x 16 floats
}

extern "C" void kernel_launch(void* const* d_in, const int* in_sizes, int n_in,
                              void* d_out, int out_size, void* d_ws, size_t ws_size,
                              hipStream_t stream) {
    const float* trip = (const float*)d_in[0];
    // d_in[1] = valid_len : unused by the reference computation
    const float* emb  = (const float*)d_in[2];
    const float* Wg   = (const float*)d_in[3];
    const float* bgp  = (const float*)d_in[4];
    const float* Wlp  = (const float*)d_in[5];
    const float* blp  = (const float*)d_in[6];
    float* out = (float*)d_out;

    // output = [trip (262144 floats) | big (4194304 floats)]
    recur_k<<<NBLK, 512, 0, stream>>>(emb, Wg, bgp, out + 262144);
    proj_expand_k<<<4096 + 256, 256, 0, stream>>>(Wlp, blp, trip, out, out + 262144);
}